// Round 3
// baseline (5055.894 us; speedup 1.0000x reference)
//
#include <hip/hip_runtime.h>
#include <stdint.h>

// ModeloNeuralVasicek: 2520-step Euler-Maruyama neural SDE, B=64 x Q=256 paths.
// One block per batch element (fully independent). Bit-exact JAX threefry RNG.
// Round 3: W2 column pinned in VGPRs via asm-opaque scalars (round 2's
// ext-vector loads were sunk back into the loop: VGPR stayed 92 -> the
// compiler re-read W2 from global every step; that was the bottleneck).
#ifndef PARTITIONABLE
#define PARTITIONABLE 1
#endif

#define NSTEPS 2520
#define NB 64
#define NT 256
#define NQ 256
#define NMAT 7

typedef float f4v __attribute__((ext_vector_type(4)));

__device__ __forceinline__ uint32_t rotl32(uint32_t v, int n) {
  return (v << n) | (v >> (32 - n));
}

// Threefry-2x32, 20 rounds — matches jax._src.prng.threefry2x32 exactly.
__device__ __forceinline__ void tf2x32(uint32_t k0, uint32_t k1,
                                       uint32_t x0, uint32_t x1,
                                       uint32_t& o0, uint32_t& o1) {
  const uint32_t k2 = k0 ^ k1 ^ 0x1BD11BDAu;
  x0 += k0; x1 += k1;
#define R4(a,b,c,d) \
  x0 += x1; x1 = rotl32(x1,(a)); x1 ^= x0; \
  x0 += x1; x1 = rotl32(x1,(b)); x1 ^= x0; \
  x0 += x1; x1 = rotl32(x1,(c)); x1 ^= x0; \
  x0 += x1; x1 = rotl32(x1,(d)); x1 ^= x0;
  R4(13,15,26,6)  x0 += k1; x1 += k2 + 1u;
  R4(17,29,16,24) x0 += k2; x1 += k0 + 2u;
  R4(13,15,26,6)  x0 += k0; x1 += k1 + 3u;
  R4(17,29,16,24) x0 += k1; x1 += k2 + 4u;
  R4(13,15,26,6)  x0 += k2; x1 += k0 + 5u;
#undef R4
  o0 = x0; o1 = x1;
}

// Eigen/XLA generic_fast_tanh_float (what XLA emits for f32 tanh).
__device__ __forceinline__ float eigen_tanh(float a_x) {
  float x = fminf(fmaxf(a_x, -7.90531110763549805f), 7.90531110763549805f);
  float x2 = x * x;
  float p = __builtin_fmaf(x2, -2.76076847742355e-16f, 2.00018790482477e-13f);
  p = __builtin_fmaf(x2, p, -8.60467152213735e-11f);
  p = __builtin_fmaf(x2, p, 5.12229709037114e-08f);
  p = __builtin_fmaf(x2, p, 1.48572235717979e-05f);
  p = __builtin_fmaf(x2, p, 6.37261928875436e-04f);
  p = __builtin_fmaf(x2, p, 4.89352455891786e-03f);
  p = x * p;
  float q = __builtin_fmaf(x2, 1.19825839466702e-06f, 1.18534705686654e-04f);
  q = __builtin_fmaf(x2, q, 2.26843463243900e-03f);
  q = __builtin_fmaf(x2, q, 4.89352518554385e-03f);
  float rr = p / q;
  return (fabsf(a_x) < 0.0004f) ? a_x : rr;
}

// Eigen/XLA generic_fast_erf_float (chlo.erf f32 lowering).
__device__ __forceinline__ float eigen_erf(float a_x) {
  float x = fminf(fmaxf(a_x, -4.0f), 4.0f);
  float x2 = x * x;
  float p = __builtin_fmaf(x2, -2.72614225801306e-10f, 2.77068142495902e-08f);
  p = __builtin_fmaf(x2, p, -2.10102402082508e-06f);
  p = __builtin_fmaf(x2, p, -5.69250639462346e-05f);
  p = __builtin_fmaf(x2, p, -7.34990630326855e-04f);
  p = __builtin_fmaf(x2, p, -2.95459980854025e-03f);
  p = __builtin_fmaf(x2, p, -1.60960333262415e-02f);
  p = x * p;
  float q = __builtin_fmaf(x2, -1.45660718464996e-05f, -2.13374055278905e-04f);
  q = __builtin_fmaf(x2, q, -1.68282697438203e-03f);
  q = __builtin_fmaf(x2, q, -7.37332916720468e-03f);
  q = __builtin_fmaf(x2, q, -1.42647390514189e-02f);
  return p / q;
}

// jax.nn.gelu(approximate=False): x * (erf(x/sqrt(2)) + 1) / 2
__device__ __forceinline__ float gelu_exact(float x) {
  float t = x / 1.41421356237309515f;
  float e = eigen_erf(t);
  return x * (e + 1.0f) * 0.5f;
}

// jax.nn.softplus = logaddexp(x, 0) = max(x,0) + log1p(exp(-|x|))
__device__ __forceinline__ float softplus_jax(float x) {
  return fmaxf(x, 0.0f) + log1pf(expf(-fabsf(x)));
}

// XLA chlo.erf_inv f32 lowering (Giles single-precision polynomial).
__device__ __forceinline__ float erfinv_xla(float x) {
  float w = -logf((1.0f - x) * (1.0f + x));
  float p;
  if (w < 5.0f) {
    w = w - 2.5f;
    p = 2.81022636e-08f;
    p = __builtin_fmaf(p, w, 3.43273939e-07f);
    p = __builtin_fmaf(p, w, -3.5233877e-06f);
    p = __builtin_fmaf(p, w, -4.39150654e-06f);
    p = __builtin_fmaf(p, w, 0.00021858087f);
    p = __builtin_fmaf(p, w, -0.00125372503f);
    p = __builtin_fmaf(p, w, -0.00417768164f);
    p = __builtin_fmaf(p, w, 0.246640727f);
    p = __builtin_fmaf(p, w, 1.50140941f);
  } else {
    w = sqrtf(w) - 3.0f;
    p = -0.000200214257f;
    p = __builtin_fmaf(p, w, 0.000100950558f);
    p = __builtin_fmaf(p, w, 0.00134934322f);
    p = __builtin_fmaf(p, w, -0.00367342844f);
    p = __builtin_fmaf(p, w, 0.00573950773f);
    p = __builtin_fmaf(p, w, -0.0076224613f);
    p = __builtin_fmaf(p, w, 0.00943887047f);
    p = __builtin_fmaf(p, w, 1.00167406f);
    p = __builtin_fmaf(p, w, 2.83297682f);
  }
  return p * x;
}

// JAX uniform(-(1-2^-24), 1) -> sqrt(2)*erfinv(u), bit-faithful.
__device__ __forceinline__ float bits_to_normal(uint32_t bits) {
  const float MINVAL = -0.999999940395355224609375f;  // nextafter(-1,0) in f32
  uint32_t fb = (bits >> 9) | 0x3F800000u;
  float f01 = __uint_as_float(fb) - 1.0f;     // [0, 1-2^-24]
  float u = f01 * 2.0f + MINVAL;              // *2 exact; add RN (matches XLA)
  u = fmaxf(u, MINVAL);
  return 1.41421356237309515f * erfinv_xla(u);
}

// ---- 128 W2 scalars: declare / load / pin / consume macros (groups of 16) ----
#define W2NAMES(G) \
  w2_##G##_0, w2_##G##_1, w2_##G##_2, w2_##G##_3, \
  w2_##G##_4, w2_##G##_5, w2_##G##_6, w2_##G##_7, \
  w2_##G##_8, w2_##G##_9, w2_##G##_10, w2_##G##_11, \
  w2_##G##_12, w2_##G##_13, w2_##G##_14, w2_##G##_15

#define W2DECL(G) float W2NAMES(G);

#define W2LOAD(G) \
  w2_##G##_0  = W2[((G)*16 +  0) * 128 + j]; \
  w2_##G##_1  = W2[((G)*16 +  1) * 128 + j]; \
  w2_##G##_2  = W2[((G)*16 +  2) * 128 + j]; \
  w2_##G##_3  = W2[((G)*16 +  3) * 128 + j]; \
  w2_##G##_4  = W2[((G)*16 +  4) * 128 + j]; \
  w2_##G##_5  = W2[((G)*16 +  5) * 128 + j]; \
  w2_##G##_6  = W2[((G)*16 +  6) * 128 + j]; \
  w2_##G##_7  = W2[((G)*16 +  7) * 128 + j]; \
  w2_##G##_8  = W2[((G)*16 +  8) * 128 + j]; \
  w2_##G##_9  = W2[((G)*16 +  9) * 128 + j]; \
  w2_##G##_10 = W2[((G)*16 + 10) * 128 + j]; \
  w2_##G##_11 = W2[((G)*16 + 11) * 128 + j]; \
  w2_##G##_12 = W2[((G)*16 + 12) * 128 + j]; \
  w2_##G##_13 = W2[((G)*16 + 13) * 128 + j]; \
  w2_##G##_14 = W2[((G)*16 + 14) * 128 + j]; \
  w2_##G##_15 = W2[((G)*16 + 15) * 128 + j];

// asm-opaque: value now originates from inline asm -> cannot be rematerialized
// as a load; register allocator must keep it live in a VGPR across the loop.
#define W2PIN(G) \
  asm volatile("" : \
    "+v"(w2_##G##_0),  "+v"(w2_##G##_1),  "+v"(w2_##G##_2),  "+v"(w2_##G##_3), \
    "+v"(w2_##G##_4),  "+v"(w2_##G##_5),  "+v"(w2_##G##_6),  "+v"(w2_##G##_7), \
    "+v"(w2_##G##_8),  "+v"(w2_##G##_9),  "+v"(w2_##G##_10), "+v"(w2_##G##_11), \
    "+v"(w2_##G##_12), "+v"(w2_##G##_13), "+v"(w2_##G##_14), "+v"(w2_##G##_15));

// layer-2 accumulation, order identical to round-1 (k≡i mod 4 chains).
#define W2SEG(G) { \
  f4v h4; \
  h4 = *(const f4v*)(hb + (G)*16 + 0); \
  a0 = __builtin_fmaf(h4[0], w2_##G##_0,  a0); \
  a1 = __builtin_fmaf(h4[1], w2_##G##_1,  a1); \
  a2 = __builtin_fmaf(h4[2], w2_##G##_2,  a2); \
  a3 = __builtin_fmaf(h4[3], w2_##G##_3,  a3); \
  h4 = *(const f4v*)(hb + (G)*16 + 4); \
  a0 = __builtin_fmaf(h4[0], w2_##G##_4,  a0); \
  a1 = __builtin_fmaf(h4[1], w2_##G##_5,  a1); \
  a2 = __builtin_fmaf(h4[2], w2_##G##_6,  a2); \
  a3 = __builtin_fmaf(h4[3], w2_##G##_7,  a3); \
  h4 = *(const f4v*)(hb + (G)*16 + 8); \
  a0 = __builtin_fmaf(h4[0], w2_##G##_8,  a0); \
  a1 = __builtin_fmaf(h4[1], w2_##G##_9,  a1); \
  a2 = __builtin_fmaf(h4[2], w2_##G##_10, a2); \
  a3 = __builtin_fmaf(h4[3], w2_##G##_11, a3); \
  h4 = *(const f4v*)(hb + (G)*16 + 12); \
  a0 = __builtin_fmaf(h4[0], w2_##G##_12, a0); \
  a1 = __builtin_fmaf(h4[1], w2_##G##_13, a1); \
  a2 = __builtin_fmaf(h4[2], w2_##G##_14, a2); \
  a3 = __builtin_fmaf(h4[3], w2_##G##_15, a3); \
}

__global__ __launch_bounds__(256, 1)
void ModeloNeuralVasicek_88158498717914_kernel(
    const float* __restrict__ X, const float* __restrict__ r_ult,
    const float* __restrict__ mats,
    const float* __restrict__ Wp, const float* __restrict__ bp,
    const float* __restrict__ ln_g, const float* __restrict__ ln_b,
    const float* __restrict__ muW1, const float* __restrict__ mub1,
    const float* __restrict__ muW2, const float* __restrict__ mub2,
    const float* __restrict__ muW3, const float* __restrict__ mub3,
    const float* __restrict__ siW1, const float* __restrict__ sib1,
    const float* __restrict__ siW2, const float* __restrict__ sib2,
    const float* __restrict__ siW3, const float* __restrict__ sib3,
    float* __restrict__ out) {
  const int b = blockIdx.x;
  const int tid = threadIdx.x;
  const int lane = tid & 63;
  const int wv = tid >> 6;

  __shared__ float part[256];
  __shared__ float mbuf[64];
  __shared__ float ctx_lds[192];
  __shared__ __align__(16) float h1_lds[256];
  __shared__ float psum[4];
  __shared__ float msum[4];
  __shared__ uint32_t kA[NSTEPS];
  __shared__ uint32_t kB[NSTEPS];

  // ---- per-step keys: jax.random.split(key(1), 2520) ----
  for (int i = tid; i < NSTEPS; i += 256) {
#if PARTITIONABLE
    uint32_t o0, o1;
    tf2x32(0u, 1u, 0u, (uint32_t)i, o0, o1);   // fold-like split: both outputs
    kA[i] = o0; kB[i] = o1;
#else
    uint32_t o0, o1, d0, d1;
    if (i < 1260) {
      tf2x32(0u, 1u, (uint32_t)(2 * i),     (uint32_t)(2 * i + 2520),     o0, d0);
      tf2x32(0u, 1u, (uint32_t)(2 * i + 1), (uint32_t)(2 * i + 1 + 2520), o1, d1);
    } else {
      tf2x32(0u, 1u, (uint32_t)(2 * i - 2520),     (uint32_t)(2 * i),     d0, o0);
      tf2x32(0u, 1u, (uint32_t)(2 * i + 1 - 2520), (uint32_t)(2 * i + 1), d1, o1);
    }
    kA[i] = o0; kB[i] = o1;
#endif
  }

  // ---- context aggregator: H = LN(tanh(X@Wp+bp)); ctx = [mean_t, std_t(ddof=1), last] ----
  float h[64];
  {
    float x0 = X[(b * NT + tid) * 2 + 0];
    float x1 = X[(b * NT + tid) * 2 + 1];
    float s = 0.f;
#pragma unroll
    for (int c = 0; c < 64; ++c) {
      float pre = __builtin_fmaf(x1, Wp[64 + c], x0 * Wp[c]) + bp[c];
      h[c] = eigen_tanh(pre);
      s += h[c];
    }
    float m = s * 0.015625f;
    float vs = 0.f;
#pragma unroll
    for (int c = 0; c < 64; ++c) { float d = h[c] - m; vs = __builtin_fmaf(d, d, vs); }
    float den = sqrtf(vs * 0.015625f + 1e-5f);
#pragma unroll
    for (int c = 0; c < 64; ++c)
      h[c] = ((h[c] - m) / den) * ln_g[c] + ln_b[c];
  }
  // channel means over T (rows live in registers; butterfly within wave, 4 partials)
#pragma unroll
  for (int c = 0; c < 64; ++c) {
    float v = h[c];
    v += __shfl_xor(v, 32, 64); v += __shfl_xor(v, 16, 64);
    v += __shfl_xor(v, 8, 64);  v += __shfl_xor(v, 4, 64);
    v += __shfl_xor(v, 2, 64);  v += __shfl_xor(v, 1, 64);
    if (lane == 0) part[wv * 64 + c] = v;
  }
  __syncthreads();
  if (tid < 64) {
    float m = ((part[tid] + part[64 + tid]) + (part[128 + tid] + part[192 + tid])) * (1.0f / 256.0f);
    mbuf[tid] = m;
    ctx_lds[tid] = m;
  }
  __syncthreads();
#pragma unroll
  for (int c = 0; c < 64; ++c) {
    float d = h[c] - mbuf[c];
    float v = d * d;
    v += __shfl_xor(v, 32, 64); v += __shfl_xor(v, 16, 64);
    v += __shfl_xor(v, 8, 64);  v += __shfl_xor(v, 4, 64);
    v += __shfl_xor(v, 2, 64);  v += __shfl_xor(v, 1, 64);
    if (lane == 0) part[wv * 64 + c] = v;
  }
  if (tid == 255) {
#pragma unroll
    for (int c = 0; c < 64; ++c) ctx_lds[128 + c] = h[c];  // H[:, -1, :]
  }
  __syncthreads();
  if (tid < 64) {
    float vs = (part[tid] + part[64 + tid]) + (part[128 + tid] + part[192 + tid]);
    ctx_lds[64 + tid] = sqrtf(vs / 255.0f);  // ddof=1
  }
  __syncthreads();

  // ---- per-thread MLP constants: thread 0..127 -> mu output j, 128..255 -> si output j ----
  const bool is_mu = tid < 128;
  const int j = is_mu ? tid : tid - 128;
  const float* W1 = is_mu ? muW1 : siW1;
  const float* W2 = is_mu ? muW2 : siW2;
  float c1 = (is_mu ? mub1 : sib1)[j];  // fold bias + constant ctx part of layer 1
  for (int c = 0; c < 192; ++c)
    c1 = __builtin_fmaf(ctx_lds[c], W1[(2 + c) * 128 + j], c1);
  const float w10 = W1[j];         // W1 row 0 (r_mean)
  const float w11 = W1[128 + j];   // W1 row 1 (t)
  const float b2s = (is_mu ? mub2 : sib2)[j];
  const float w3s = (is_mu ? muW3 : siW3)[j];
  const float b3mu = mub3[0];
  const float b3si = sib3[0];

  // W2 column j: 128 asm-opaque scalars, guaranteed VGPR-resident.
  W2DECL(0) W2DECL(1) W2DECL(2) W2DECL(3)
  W2DECL(4) W2DECL(5) W2DECL(6) W2DECL(7)
  W2LOAD(0) W2LOAD(1) W2LOAD(2) W2LOAD(3)
  W2LOAD(4) W2LOAD(5) W2LOAD(6) W2LOAD(7)
  W2PIN(0) W2PIN(1) W2PIN(2) W2PIN(3)
  W2PIN(4) W2PIN(5) W2PIN(6) W2PIN(7)

  // ---- path state: thread q owns path q of batch b ----
  float r = r_ult[b];
  float area = 0.f;
  const uint32_t cnt = (uint32_t)(b * NQ + tid);  // linear index into (B,Q)

  const float DTF = (float)(1.0 / 252.0);
  const float SQDT = 0.06299407883487120442f;  // f32(sqrt(1/252))
  const float TSTEP = 1.0f / 2519.0f;          // linspace(0,1,2520) step

#pragma unroll 1
  for (int s = 0; s < NSTEPS; ++s) {
    // dW first: ~180 independent VALU ops fill the shuffle-chain bubbles below
    uint32_t q0, q1;
#if PARTITIONABLE
    tf2x32(kA[s], kB[s], 0u, cnt, q0, q1);
    const uint32_t bits = q0 ^ q1;
#else
    const uint32_t c0 = (cnt < 8192u) ? cnt : (cnt - 8192u);
    tf2x32(kA[s], kB[s], c0, c0 + 8192u, q0, q1);
    const uint32_t bits = (cnt < 8192u) ? q0 : q1;
#endif
    const float dW = bits_to_normal(bits) * SQDT;

    // r.mean over 256 paths
    float v = r;
    v += __shfl_xor(v, 32, 64); v += __shfl_xor(v, 16, 64);
    v += __shfl_xor(v, 8, 64);  v += __shfl_xor(v, 4, 64);
    v += __shfl_xor(v, 2, 64);  v += __shfl_xor(v, 1, 64);
    if (lane == 0) psum[wv] = v;
    __syncthreads();  // barrier 1
    const float r_mean = ((psum[0] + psum[1]) + (psum[2] + psum[3])) * (1.0f / 256.0f);
    const float tval = TSTEP * (float)s;

    // layer 1 (ctx part precomputed): 2 FMAs + gelu
    float pre = __builtin_fmaf(tval, w11, __builtin_fmaf(r_mean, w10, c1));
    h1_lds[tid] = gelu_exact(pre);
    __syncthreads();  // barrier 2

    // layer 2: 128-MAC dot; h1 via LDS float4 broadcasts, W2 in pinned VGPRs
    const float* hb = h1_lds + (is_mu ? 0 : 128);
    float a0 = 0.f, a1 = 0.f, a2 = 0.f, a3 = 0.f;
    W2SEG(0) W2SEG(1) W2SEG(2) W2SEG(3)
    W2SEG(4) W2SEG(5) W2SEG(6) W2SEG(7)
    float h2 = ((a0 + a1) + (a2 + a3)) + b2s;

    // layer 3: dot over 128 outputs = 2-wave reduction
    float p = gelu_exact(h2) * w3s;
    p += __shfl_xor(p, 32, 64); p += __shfl_xor(p, 16, 64);
    p += __shfl_xor(p, 8, 64);  p += __shfl_xor(p, 4, 64);
    p += __shfl_xor(p, 2, 64);  p += __shfl_xor(p, 1, 64);
    if (lane == 0) msum[wv] = p;
    __syncthreads();  // barrier 3
    const float mu = (msum[0] + msum[1]) + b3mu;
    const float si_raw = (msum[2] + msum[3]) + b3si;
    const float si = softplus_jax(si_raw) + 1e-5f;

    // r = (r + mu*DT) + si*dW ; area += r*DT — non-fused to mirror XLA elementwise
    r = __fadd_rn(__fadd_rn(r, __fmul_rn(mu, DTF)), __fmul_rn(si, dW));
    area = __fadd_rn(area, __fmul_rn(r, DTF));
  }

  // area.mean(1) then output: (am * (m/maxT)) / m for each maturity
  float v2 = area;
  v2 += __shfl_xor(v2, 32, 64); v2 += __shfl_xor(v2, 16, 64);
  v2 += __shfl_xor(v2, 8, 64);  v2 += __shfl_xor(v2, 4, 64);
  v2 += __shfl_xor(v2, 2, 64);  v2 += __shfl_xor(v2, 1, 64);
  if (lane == 0) psum[wv] = v2;
  __syncthreads();
  if (tid < NMAT) {
    const float am = ((psum[0] + psum[1]) + (psum[2] + psum[3])) * (1.0f / 256.0f);
    float mx = mats[0];
#pragma unroll
    for (int i = 1; i < NMAT; ++i) mx = fmaxf(mx, mats[i]);
    const float m = mats[tid];
    const float frac = m / (mx + 1e-12f);
    out[b * NMAT + tid] = (am * frac) / (m + 1e-12f);
  }
}

extern "C" void kernel_launch(void* const* d_in, const int* in_sizes, int n_in,
                              void* d_out, int out_size, void* d_ws, size_t ws_size,
                              hipStream_t stream) {
  (void)in_sizes; (void)n_in; (void)d_ws; (void)ws_size; (void)out_size;
  const float* X      = (const float*)d_in[0];
  const float* r_ult  = (const float*)d_in[1];
  const float* mats   = (const float*)d_in[2];
  const float* Wp     = (const float*)d_in[3];
  const float* bp     = (const float*)d_in[4];
  const float* ln_g   = (const float*)d_in[5];
  const float* ln_b   = (const float*)d_in[6];
  const float* muW1   = (const float*)d_in[7];
  const float* mub1   = (const float*)d_in[8];
  const float* muW2   = (const float*)d_in[9];
  const float* mub2   = (const float*)d_in[10];
  const float* muW3   = (const float*)d_in[11];
  const float* mub3   = (const float*)d_in[12];
  const float* siW1   = (const float*)d_in[13];
  const float* sib1   = (const float*)d_in[14];
  const float* siW2   = (const float*)d_in[15];
  const float* sib2   = (const float*)d_in[16];
  const float* siW3   = (const float*)d_in[17];
  const float* sib3   = (const float*)d_in[18];
  hipLaunchKernelGGL(ModeloNeuralVasicek_88158498717914_kernel,
                     dim3(NB), dim3(256), 0, stream,
                     X, r_ult, mats, Wp, bp, ln_g, ln_b,
                     muW1, mub1, muW2, mub2, muW3, mub3,
                     siW1, sib1, siW2, sib2, siW3, sib3,
                     (float*)d_out);
}

// Round 4
// 4870.218 us; speedup vs baseline: 1.0381x; 1.0381x over previous
//
#include <hip/hip_runtime.h>
#include <stdint.h>

// ModeloNeuralVasicek: 2520-step Euler-Maruyama neural SDE, B=64 x Q=256 paths.
// One block per batch element (fully independent). Bit-exact JAX threefry RNG.
// Round 4: amdgpu_waves_per_eu(1,1) to lift the backend's VGPR ceiling.
// Rounds 1-3 all compiled to VGPR_Count=92 (array->scratch, ext-vec->re-load,
// asm-pin->spill): the scheduler's occupancy target capped the budget; the
// launch_bounds 2nd arg only sets a MIN waves/EU. Explicit (1,1) => 512 VGPRs.
#ifndef PARTITIONABLE
#define PARTITIONABLE 1
#endif

#define NSTEPS 2520
#define NB 64
#define NT 256
#define NQ 256
#define NMAT 7

typedef float f4v __attribute__((ext_vector_type(4)));

__device__ __forceinline__ uint32_t rotl32(uint32_t v, int n) {
  return (v << n) | (v >> (32 - n));
}

// Threefry-2x32, 20 rounds — matches jax._src.prng.threefry2x32 exactly.
__device__ __forceinline__ void tf2x32(uint32_t k0, uint32_t k1,
                                       uint32_t x0, uint32_t x1,
                                       uint32_t& o0, uint32_t& o1) {
  const uint32_t k2 = k0 ^ k1 ^ 0x1BD11BDAu;
  x0 += k0; x1 += k1;
#define R4(a,b,c,d) \
  x0 += x1; x1 = rotl32(x1,(a)); x1 ^= x0; \
  x0 += x1; x1 = rotl32(x1,(b)); x1 ^= x0; \
  x0 += x1; x1 = rotl32(x1,(c)); x1 ^= x0; \
  x0 += x1; x1 = rotl32(x1,(d)); x1 ^= x0;
  R4(13,15,26,6)  x0 += k1; x1 += k2 + 1u;
  R4(17,29,16,24) x0 += k2; x1 += k0 + 2u;
  R4(13,15,26,6)  x0 += k0; x1 += k1 + 3u;
  R4(17,29,16,24) x0 += k1; x1 += k2 + 4u;
  R4(13,15,26,6)  x0 += k2; x1 += k0 + 5u;
#undef R4
  o0 = x0; o1 = x1;
}

// Eigen/XLA generic_fast_tanh_float (what XLA emits for f32 tanh).
__device__ __forceinline__ float eigen_tanh(float a_x) {
  float x = fminf(fmaxf(a_x, -7.90531110763549805f), 7.90531110763549805f);
  float x2 = x * x;
  float p = __builtin_fmaf(x2, -2.76076847742355e-16f, 2.00018790482477e-13f);
  p = __builtin_fmaf(x2, p, -8.60467152213735e-11f);
  p = __builtin_fmaf(x2, p, 5.12229709037114e-08f);
  p = __builtin_fmaf(x2, p, 1.48572235717979e-05f);
  p = __builtin_fmaf(x2, p, 6.37261928875436e-04f);
  p = __builtin_fmaf(x2, p, 4.89352455891786e-03f);
  p = x * p;
  float q = __builtin_fmaf(x2, 1.19825839466702e-06f, 1.18534705686654e-04f);
  q = __builtin_fmaf(x2, q, 2.26843463243900e-03f);
  q = __builtin_fmaf(x2, q, 4.89352518554385e-03f);
  float rr = p / q;
  return (fabsf(a_x) < 0.0004f) ? a_x : rr;
}

// Eigen/XLA generic_fast_erf_float (chlo.erf f32 lowering).
__device__ __forceinline__ float eigen_erf(float a_x) {
  float x = fminf(fmaxf(a_x, -4.0f), 4.0f);
  float x2 = x * x;
  float p = __builtin_fmaf(x2, -2.72614225801306e-10f, 2.77068142495902e-08f);
  p = __builtin_fmaf(x2, p, -2.10102402082508e-06f);
  p = __builtin_fmaf(x2, p, -5.69250639462346e-05f);
  p = __builtin_fmaf(x2, p, -7.34990630326855e-04f);
  p = __builtin_fmaf(x2, p, -2.95459980854025e-03f);
  p = __builtin_fmaf(x2, p, -1.60960333262415e-02f);
  p = x * p;
  float q = __builtin_fmaf(x2, -1.45660718464996e-05f, -2.13374055278905e-04f);
  q = __builtin_fmaf(x2, q, -1.68282697438203e-03f);
  q = __builtin_fmaf(x2, q, -7.37332916720468e-03f);
  q = __builtin_fmaf(x2, q, -1.42647390514189e-02f);
  return p / q;
}

// jax.nn.gelu(approximate=False): x * (erf(x/sqrt(2)) + 1) / 2
__device__ __forceinline__ float gelu_exact(float x) {
  float t = x / 1.41421356237309515f;
  float e = eigen_erf(t);
  return x * (e + 1.0f) * 0.5f;
}

// jax.nn.softplus = logaddexp(x, 0) = max(x,0) + log1p(exp(-|x|))
__device__ __forceinline__ float softplus_jax(float x) {
  return fmaxf(x, 0.0f) + log1pf(expf(-fabsf(x)));
}

// XLA chlo.erf_inv f32 lowering (Giles single-precision polynomial).
__device__ __forceinline__ float erfinv_xla(float x) {
  float w = -logf((1.0f - x) * (1.0f + x));
  float p;
  if (w < 5.0f) {
    w = w - 2.5f;
    p = 2.81022636e-08f;
    p = __builtin_fmaf(p, w, 3.43273939e-07f);
    p = __builtin_fmaf(p, w, -3.5233877e-06f);
    p = __builtin_fmaf(p, w, -4.39150654e-06f);
    p = __builtin_fmaf(p, w, 0.00021858087f);
    p = __builtin_fmaf(p, w, -0.00125372503f);
    p = __builtin_fmaf(p, w, -0.00417768164f);
    p = __builtin_fmaf(p, w, 0.246640727f);
    p = __builtin_fmaf(p, w, 1.50140941f);
  } else {
    w = sqrtf(w) - 3.0f;
    p = -0.000200214257f;
    p = __builtin_fmaf(p, w, 0.000100950558f);
    p = __builtin_fmaf(p, w, 0.00134934322f);
    p = __builtin_fmaf(p, w, -0.00367342844f);
    p = __builtin_fmaf(p, w, 0.00573950773f);
    p = __builtin_fmaf(p, w, -0.0076224613f);
    p = __builtin_fmaf(p, w, 0.00943887047f);
    p = __builtin_fmaf(p, w, 1.00167406f);
    p = __builtin_fmaf(p, w, 2.83297682f);
  }
  return p * x;
}

// JAX uniform(-(1-2^-24), 1) -> sqrt(2)*erfinv(u), bit-faithful.
__device__ __forceinline__ float bits_to_normal(uint32_t bits) {
  const float MINVAL = -0.999999940395355224609375f;  // nextafter(-1,0) in f32
  uint32_t fb = (bits >> 9) | 0x3F800000u;
  float f01 = __uint_as_float(fb) - 1.0f;     // [0, 1-2^-24]
  float u = f01 * 2.0f + MINVAL;              // *2 exact; add RN (matches XLA)
  u = fmaxf(u, MINVAL);
  return 1.41421356237309515f * erfinv_xla(u);
}

// ---- 128 W2 scalars: declare / load / pin / consume macros (groups of 16) ----
#define W2NAMES(G) \
  w2_##G##_0, w2_##G##_1, w2_##G##_2, w2_##G##_3, \
  w2_##G##_4, w2_##G##_5, w2_##G##_6, w2_##G##_7, \
  w2_##G##_8, w2_##G##_9, w2_##G##_10, w2_##G##_11, \
  w2_##G##_12, w2_##G##_13, w2_##G##_14, w2_##G##_15

#define W2DECL(G) float W2NAMES(G);

#define W2LOAD(G) \
  w2_##G##_0  = W2[((G)*16 +  0) * 128 + j]; \
  w2_##G##_1  = W2[((G)*16 +  1) * 128 + j]; \
  w2_##G##_2  = W2[((G)*16 +  2) * 128 + j]; \
  w2_##G##_3  = W2[((G)*16 +  3) * 128 + j]; \
  w2_##G##_4  = W2[((G)*16 +  4) * 128 + j]; \
  w2_##G##_5  = W2[((G)*16 +  5) * 128 + j]; \
  w2_##G##_6  = W2[((G)*16 +  6) * 128 + j]; \
  w2_##G##_7  = W2[((G)*16 +  7) * 128 + j]; \
  w2_##G##_8  = W2[((G)*16 +  8) * 128 + j]; \
  w2_##G##_9  = W2[((G)*16 +  9) * 128 + j]; \
  w2_##G##_10 = W2[((G)*16 + 10) * 128 + j]; \
  w2_##G##_11 = W2[((G)*16 + 11) * 128 + j]; \
  w2_##G##_12 = W2[((G)*16 + 12) * 128 + j]; \
  w2_##G##_13 = W2[((G)*16 + 13) * 128 + j]; \
  w2_##G##_14 = W2[((G)*16 + 14) * 128 + j]; \
  w2_##G##_15 = W2[((G)*16 + 15) * 128 + j];

// asm-opaque: value originates from inline asm -> cannot be rematerialized as
// a load; with the waves_per_eu(1,1) budget the allocator keeps them in VGPRs.
#define W2PIN(G) \
  asm volatile("" : \
    "+v"(w2_##G##_0),  "+v"(w2_##G##_1),  "+v"(w2_##G##_2),  "+v"(w2_##G##_3), \
    "+v"(w2_##G##_4),  "+v"(w2_##G##_5),  "+v"(w2_##G##_6),  "+v"(w2_##G##_7), \
    "+v"(w2_##G##_8),  "+v"(w2_##G##_9),  "+v"(w2_##G##_10), "+v"(w2_##G##_11), \
    "+v"(w2_##G##_12), "+v"(w2_##G##_13), "+v"(w2_##G##_14), "+v"(w2_##G##_15));

// layer-2 accumulation, order identical to round-1 (k≡i mod 4 chains).
#define W2SEG(G) { \
  f4v h4; \
  h4 = *(const f4v*)(hb + (G)*16 + 0); \
  a0 = __builtin_fmaf(h4[0], w2_##G##_0,  a0); \
  a1 = __builtin_fmaf(h4[1], w2_##G##_1,  a1); \
  a2 = __builtin_fmaf(h4[2], w2_##G##_2,  a2); \
  a3 = __builtin_fmaf(h4[3], w2_##G##_3,  a3); \
  h4 = *(const f4v*)(hb + (G)*16 + 4); \
  a0 = __builtin_fmaf(h4[0], w2_##G##_4,  a0); \
  a1 = __builtin_fmaf(h4[1], w2_##G##_5,  a1); \
  a2 = __builtin_fmaf(h4[2], w2_##G##_6,  a2); \
  a3 = __builtin_fmaf(h4[3], w2_##G##_7,  a3); \
  h4 = *(const f4v*)(hb + (G)*16 + 8); \
  a0 = __builtin_fmaf(h4[0], w2_##G##_8,  a0); \
  a1 = __builtin_fmaf(h4[1], w2_##G##_9,  a1); \
  a2 = __builtin_fmaf(h4[2], w2_##G##_10, a2); \
  a3 = __builtin_fmaf(h4[3], w2_##G##_11, a3); \
  h4 = *(const f4v*)(hb + (G)*16 + 12); \
  a0 = __builtin_fmaf(h4[0], w2_##G##_12, a0); \
  a1 = __builtin_fmaf(h4[1], w2_##G##_13, a1); \
  a2 = __builtin_fmaf(h4[2], w2_##G##_14, a2); \
  a3 = __builtin_fmaf(h4[3], w2_##G##_15, a3); \
}

__global__
__attribute__((amdgpu_flat_work_group_size(256, 256)))
__attribute__((amdgpu_waves_per_eu(1, 1)))
void ModeloNeuralVasicek_88158498717914_kernel(
    const float* __restrict__ X, const float* __restrict__ r_ult,
    const float* __restrict__ mats,
    const float* __restrict__ Wp, const float* __restrict__ bp,
    const float* __restrict__ ln_g, const float* __restrict__ ln_b,
    const float* __restrict__ muW1, const float* __restrict__ mub1,
    const float* __restrict__ muW2, const float* __restrict__ mub2,
    const float* __restrict__ muW3, const float* __restrict__ mub3,
    const float* __restrict__ siW1, const float* __restrict__ sib1,
    const float* __restrict__ siW2, const float* __restrict__ sib2,
    const float* __restrict__ siW3, const float* __restrict__ sib3,
    float* __restrict__ out) {
  const int b = blockIdx.x;
  const int tid = threadIdx.x;
  const int lane = tid & 63;
  const int wv = tid >> 6;

  __shared__ float part[256];
  __shared__ float mbuf[64];
  __shared__ float ctx_lds[192];
  __shared__ __align__(16) float h1_lds[256];
  __shared__ float psum[4];
  __shared__ float msum[4];
  __shared__ uint32_t kA[NSTEPS];
  __shared__ uint32_t kB[NSTEPS];

  // ---- per-step keys: jax.random.split(key(1), 2520) ----
  for (int i = tid; i < NSTEPS; i += 256) {
#if PARTITIONABLE
    uint32_t o0, o1;
    tf2x32(0u, 1u, 0u, (uint32_t)i, o0, o1);   // fold-like split: both outputs
    kA[i] = o0; kB[i] = o1;
#else
    uint32_t o0, o1, d0, d1;
    if (i < 1260) {
      tf2x32(0u, 1u, (uint32_t)(2 * i),     (uint32_t)(2 * i + 2520),     o0, d0);
      tf2x32(0u, 1u, (uint32_t)(2 * i + 1), (uint32_t)(2 * i + 1 + 2520), o1, d1);
    } else {
      tf2x32(0u, 1u, (uint32_t)(2 * i - 2520),     (uint32_t)(2 * i),     d0, o0);
      tf2x32(0u, 1u, (uint32_t)(2 * i + 1 - 2520), (uint32_t)(2 * i + 1), d1, o1);
    }
    kA[i] = o0; kB[i] = o1;
#endif
  }

  // ---- context aggregator: H = LN(tanh(X@Wp+bp)); ctx = [mean_t, std_t(ddof=1), last] ----
  float h[64];
  {
    float x0 = X[(b * NT + tid) * 2 + 0];
    float x1 = X[(b * NT + tid) * 2 + 1];
    float s = 0.f;
#pragma unroll
    for (int c = 0; c < 64; ++c) {
      float pre = __builtin_fmaf(x1, Wp[64 + c], x0 * Wp[c]) + bp[c];
      h[c] = eigen_tanh(pre);
      s += h[c];
    }
    float m = s * 0.015625f;
    float vs = 0.f;
#pragma unroll
    for (int c = 0; c < 64; ++c) { float d = h[c] - m; vs = __builtin_fmaf(d, d, vs); }
    float den = sqrtf(vs * 0.015625f + 1e-5f);
#pragma unroll
    for (int c = 0; c < 64; ++c)
      h[c] = ((h[c] - m) / den) * ln_g[c] + ln_b[c];
  }
  // channel means over T (rows live in registers; butterfly within wave, 4 partials)
#pragma unroll
  for (int c = 0; c < 64; ++c) {
    float v = h[c];
    v += __shfl_xor(v, 32, 64); v += __shfl_xor(v, 16, 64);
    v += __shfl_xor(v, 8, 64);  v += __shfl_xor(v, 4, 64);
    v += __shfl_xor(v, 2, 64);  v += __shfl_xor(v, 1, 64);
    if (lane == 0) part[wv * 64 + c] = v;
  }
  __syncthreads();
  if (tid < 64) {
    float m = ((part[tid] + part[64 + tid]) + (part[128 + tid] + part[192 + tid])) * (1.0f / 256.0f);
    mbuf[tid] = m;
    ctx_lds[tid] = m;
  }
  __syncthreads();
#pragma unroll
  for (int c = 0; c < 64; ++c) {
    float d = h[c] - mbuf[c];
    float v = d * d;
    v += __shfl_xor(v, 32, 64); v += __shfl_xor(v, 16, 64);
    v += __shfl_xor(v, 8, 64);  v += __shfl_xor(v, 4, 64);
    v += __shfl_xor(v, 2, 64);  v += __shfl_xor(v, 1, 64);
    if (lane == 0) part[wv * 64 + c] = v;
  }
  if (tid == 255) {
#pragma unroll
    for (int c = 0; c < 64; ++c) ctx_lds[128 + c] = h[c];  // H[:, -1, :]
  }
  __syncthreads();
  if (tid < 64) {
    float vs = (part[tid] + part[64 + tid]) + (part[128 + tid] + part[192 + tid]);
    ctx_lds[64 + tid] = sqrtf(vs / 255.0f);  // ddof=1
  }
  __syncthreads();

  // ---- per-thread MLP constants: thread 0..127 -> mu output j, 128..255 -> si output j ----
  const bool is_mu = tid < 128;
  const int j = is_mu ? tid : tid - 128;
  const float* W1 = is_mu ? muW1 : siW1;
  const float* W2 = is_mu ? muW2 : siW2;
  float c1 = (is_mu ? mub1 : sib1)[j];  // fold bias + constant ctx part of layer 1
  for (int c = 0; c < 192; ++c)
    c1 = __builtin_fmaf(ctx_lds[c], W1[(2 + c) * 128 + j], c1);
  const float w10 = W1[j];         // W1 row 0 (r_mean)
  const float w11 = W1[128 + j];   // W1 row 1 (t)
  const float b2s = (is_mu ? mub2 : sib2)[j];
  const float w3s = (is_mu ? muW3 : siW3)[j];
  const float b3mu = mub3[0];
  const float b3si = sib3[0];

  // W2 column j: 128 asm-opaque scalars, VGPR-resident under waves_per_eu(1,1).
  W2DECL(0) W2DECL(1) W2DECL(2) W2DECL(3)
  W2DECL(4) W2DECL(5) W2DECL(6) W2DECL(7)
  W2LOAD(0) W2LOAD(1) W2LOAD(2) W2LOAD(3)
  W2LOAD(4) W2LOAD(5) W2LOAD(6) W2LOAD(7)
  W2PIN(0) W2PIN(1) W2PIN(2) W2PIN(3)
  W2PIN(4) W2PIN(5) W2PIN(6) W2PIN(7)

  // ---- path state: thread q owns path q of batch b ----
  float r = r_ult[b];
  float area = 0.f;
  const uint32_t cnt = (uint32_t)(b * NQ + tid);  // linear index into (B,Q)

  const float DTF = (float)(1.0 / 252.0);
  const float SQDT = 0.06299407883487120442f;  // f32(sqrt(1/252))
  const float TSTEP = 1.0f / 2519.0f;          // linspace(0,1,2520) step

#pragma unroll 1
  for (int s = 0; s < NSTEPS; ++s) {
    // r.mean over 256 paths — the serial critical path; start it immediately
    float v = r;
    v += __shfl_xor(v, 32, 64); v += __shfl_xor(v, 16, 64);
    v += __shfl_xor(v, 8, 64);  v += __shfl_xor(v, 4, 64);
    v += __shfl_xor(v, 2, 64);  v += __shfl_xor(v, 1, 64);
    if (lane == 0) psum[wv] = v;
    __syncthreads();  // barrier 1
    const float r_mean = ((psum[0] + psum[1]) + (psum[2] + psum[3])) * (1.0f / 256.0f);
    const float tval = TSTEP * (float)s;

    // dW: independent of MLP chain — scheduler overlaps it with layer 1
    uint32_t q0, q1;
#if PARTITIONABLE
    tf2x32(kA[s], kB[s], 0u, cnt, q0, q1);
    const uint32_t bits = q0 ^ q1;
#else
    const uint32_t c0 = (cnt < 8192u) ? cnt : (cnt - 8192u);
    tf2x32(kA[s], kB[s], c0, c0 + 8192u, q0, q1);
    const uint32_t bits = (cnt < 8192u) ? q0 : q1;
#endif
    const float dW = bits_to_normal(bits) * SQDT;

    // layer 1 (ctx part precomputed): 2 FMAs + gelu
    float pre = __builtin_fmaf(tval, w11, __builtin_fmaf(r_mean, w10, c1));
    h1_lds[tid] = gelu_exact(pre);
    __syncthreads();  // barrier 2

    // layer 2: 128-MAC dot; h1 via LDS float4 broadcasts, W2 in pinned VGPRs
    const float* hb = h1_lds + (is_mu ? 0 : 128);
    float a0 = 0.f, a1 = 0.f, a2 = 0.f, a3 = 0.f;
    W2SEG(0) W2SEG(1) W2SEG(2) W2SEG(3)
    W2SEG(4) W2SEG(5) W2SEG(6) W2SEG(7)
    float h2 = ((a0 + a1) + (a2 + a3)) + b2s;

    // layer 3: dot over 128 outputs = 2-wave reduction
    float p = gelu_exact(h2) * w3s;
    p += __shfl_xor(p, 32, 64); p += __shfl_xor(p, 16, 64);
    p += __shfl_xor(p, 8, 64);  p += __shfl_xor(p, 4, 64);
    p += __shfl_xor(p, 2, 64);  p += __shfl_xor(p, 1, 64);
    if (lane == 0) msum[wv] = p;
    __syncthreads();  // barrier 3
    const float mu = (msum[0] + msum[1]) + b3mu;
    const float si_raw = (msum[2] + msum[3]) + b3si;
    const float si = softplus_jax(si_raw) + 1e-5f;

    // r = (r + mu*DT) + si*dW ; area += r*DT — non-fused to mirror XLA elementwise
    r = __fadd_rn(__fadd_rn(r, __fmul_rn(mu, DTF)), __fmul_rn(si, dW));
    area = __fadd_rn(area, __fmul_rn(r, DTF));
  }

  // area.mean(1) then output: (am * (m/maxT)) / m for each maturity
  float v2 = area;
  v2 += __shfl_xor(v2, 32, 64); v2 += __shfl_xor(v2, 16, 64);
  v2 += __shfl_xor(v2, 8, 64);  v2 += __shfl_xor(v2, 4, 64);
  v2 += __shfl_xor(v2, 2, 64);  v2 += __shfl_xor(v2, 1, 64);
  if (lane == 0) psum[wv] = v2;
  __syncthreads();
  if (tid < NMAT) {
    const float am = ((psum[0] + psum[1]) + (psum[2] + psum[3])) * (1.0f / 256.0f);
    float mx = mats[0];
#pragma unroll
    for (int i = 1; i < NMAT; ++i) mx = fmaxf(mx, mats[i]);
    const float m = mats[tid];
    const float frac = m / (mx + 1e-12f);
    out[b * NMAT + tid] = (am * frac) / (m + 1e-12f);
  }
}

extern "C" void kernel_launch(void* const* d_in, const int* in_sizes, int n_in,
                              void* d_out, int out_size, void* d_ws, size_t ws_size,
                              hipStream_t stream) {
  (void)in_sizes; (void)n_in; (void)d_ws; (void)ws_size; (void)out_size;
  const float* X      = (const float*)d_in[0];
  const float* r_ult  = (const float*)d_in[1];
  const float* mats   = (const float*)d_in[2];
  const float* Wp     = (const float*)d_in[3];
  const float* bp     = (const float*)d_in[4];
  const float* ln_g   = (const float*)d_in[5];
  const float* ln_b   = (const float*)d_in[6];
  const float* muW1   = (const float*)d_in[7];
  const float* mub1   = (const float*)d_in[8];
  const float* muW2   = (const float*)d_in[9];
  const float* mub2   = (const float*)d_in[10];
  const float* muW3   = (const float*)d_in[11];
  const float* mub3   = (const float*)d_in[12];
  const float* siW1   = (const float*)d_in[13];
  const float* sib1   = (const float*)d_in[14];
  const float* siW2   = (const float*)d_in[15];
  const float* sib2   = (const float*)d_in[16];
  const float* siW3   = (const float*)d_in[17];
  const float* sib3   = (const float*)d_in[18];
  hipLaunchKernelGGL(ModeloNeuralVasicek_88158498717914_kernel,
                     dim3(NB), dim3(256), 0, stream,
                     X, r_ult, mats, Wp, bp, ln_g, ln_b,
                     muW1, mub1, muW2, mub2, muW3, mub3,
                     siW1, sib1, siW2, sib2, siW3, sib3,
                     (float*)d_out);
}

// Round 5
// 4383.681 us; speedup vs baseline: 1.1533x; 1.1110x over previous
//
#include <hip/hip_runtime.h>
#include <stdint.h>

// ModeloNeuralVasicek — decoupled two-phase formulation.
// Key identity: paths couple to the MLPs only via r.mean, and dW is
// independent of r. So the per-step mean follows the scalar recursion
//   r_mean' = r_mean + mu(r_mean,t,ctx)*DT + si(.)*mean_q(dW)
// and the output needs only mean_q(area) = DT * sum_s r_mean.
// Phase 1 (full GPU): mean_dW[b][s] over q — 41M threefry normals, parallel.
// Phase 2 (64 blocks x 512 thr): sequential 2520-step scalar recursion; each
// thread holds a 64-float W2 half-column (fits the default VGPR budget, which
// rounds 1-4 proved is what the allocator actually honors).
// Not bit-exact vs reference (mean reordering); est. error ~1e-4 << 5.4e-2.

#define NSTEPS 2520
#define NB 64
#define NT 256
#define NQ 256
#define NMAT 7

typedef float f16v __attribute__((ext_vector_type(16)));
typedef float f4v  __attribute__((ext_vector_type(4)));

__device__ __forceinline__ uint32_t rotl32(uint32_t v, int n) {
  return (v << n) | (v >> (32 - n));
}

// Threefry-2x32, 20 rounds — matches jax._src.prng.threefry2x32 exactly.
__device__ __forceinline__ void tf2x32(uint32_t k0, uint32_t k1,
                                       uint32_t x0, uint32_t x1,
                                       uint32_t& o0, uint32_t& o1) {
  const uint32_t k2 = k0 ^ k1 ^ 0x1BD11BDAu;
  x0 += k0; x1 += k1;
#define R4(a,b,c,d) \
  x0 += x1; x1 = rotl32(x1,(a)); x1 ^= x0; \
  x0 += x1; x1 = rotl32(x1,(b)); x1 ^= x0; \
  x0 += x1; x1 = rotl32(x1,(c)); x1 ^= x0; \
  x0 += x1; x1 = rotl32(x1,(d)); x1 ^= x0;
  R4(13,15,26,6)  x0 += k1; x1 += k2 + 1u;
  R4(17,29,16,24) x0 += k2; x1 += k0 + 2u;
  R4(13,15,26,6)  x0 += k0; x1 += k1 + 3u;
  R4(17,29,16,24) x0 += k1; x1 += k2 + 4u;
  R4(13,15,26,6)  x0 += k2; x1 += k0 + 5u;
#undef R4
  o0 = x0; o1 = x1;
}

// Eigen/XLA generic_fast_tanh_float.
__device__ __forceinline__ float eigen_tanh(float a_x) {
  float x = fminf(fmaxf(a_x, -7.90531110763549805f), 7.90531110763549805f);
  float x2 = x * x;
  float p = __builtin_fmaf(x2, -2.76076847742355e-16f, 2.00018790482477e-13f);
  p = __builtin_fmaf(x2, p, -8.60467152213735e-11f);
  p = __builtin_fmaf(x2, p, 5.12229709037114e-08f);
  p = __builtin_fmaf(x2, p, 1.48572235717979e-05f);
  p = __builtin_fmaf(x2, p, 6.37261928875436e-04f);
  p = __builtin_fmaf(x2, p, 4.89352455891786e-03f);
  p = x * p;
  float q = __builtin_fmaf(x2, 1.19825839466702e-06f, 1.18534705686654e-04f);
  q = __builtin_fmaf(x2, q, 2.26843463243900e-03f);
  q = __builtin_fmaf(x2, q, 4.89352518554385e-03f);
  float rr = p / q;
  return (fabsf(a_x) < 0.0004f) ? a_x : rr;
}

// Eigen/XLA generic_fast_erf_float.
__device__ __forceinline__ float eigen_erf(float a_x) {
  float x = fminf(fmaxf(a_x, -4.0f), 4.0f);
  float x2 = x * x;
  float p = __builtin_fmaf(x2, -2.72614225801306e-10f, 2.77068142495902e-08f);
  p = __builtin_fmaf(x2, p, -2.10102402082508e-06f);
  p = __builtin_fmaf(x2, p, -5.69250639462346e-05f);
  p = __builtin_fmaf(x2, p, -7.34990630326855e-04f);
  p = __builtin_fmaf(x2, p, -2.95459980854025e-03f);
  p = __builtin_fmaf(x2, p, -1.60960333262415e-02f);
  p = x * p;
  float q = __builtin_fmaf(x2, -1.45660718464996e-05f, -2.13374055278905e-04f);
  q = __builtin_fmaf(x2, q, -1.68282697438203e-03f);
  q = __builtin_fmaf(x2, q, -7.37332916720468e-03f);
  q = __builtin_fmaf(x2, q, -1.42647390514189e-02f);
  return p / q;
}

__device__ __forceinline__ float gelu_exact(float x) {
  float t = x / 1.41421356237309515f;
  float e = eigen_erf(t);
  return x * (e + 1.0f) * 0.5f;
}

__device__ __forceinline__ float softplus_jax(float x) {
  return fmaxf(x, 0.0f) + log1pf(expf(-fabsf(x)));
}

// XLA chlo.erf_inv f32 (Giles polynomial).
__device__ __forceinline__ float erfinv_xla(float x) {
  float w = -logf((1.0f - x) * (1.0f + x));
  float p;
  if (w < 5.0f) {
    w = w - 2.5f;
    p = 2.81022636e-08f;
    p = __builtin_fmaf(p, w, 3.43273939e-07f);
    p = __builtin_fmaf(p, w, -3.5233877e-06f);
    p = __builtin_fmaf(p, w, -4.39150654e-06f);
    p = __builtin_fmaf(p, w, 0.00021858087f);
    p = __builtin_fmaf(p, w, -0.00125372503f);
    p = __builtin_fmaf(p, w, -0.00417768164f);
    p = __builtin_fmaf(p, w, 0.246640727f);
    p = __builtin_fmaf(p, w, 1.50140941f);
  } else {
    w = sqrtf(w) - 3.0f;
    p = -0.000200214257f;
    p = __builtin_fmaf(p, w, 0.000100950558f);
    p = __builtin_fmaf(p, w, 0.00134934322f);
    p = __builtin_fmaf(p, w, -0.00367342844f);
    p = __builtin_fmaf(p, w, 0.00573950773f);
    p = __builtin_fmaf(p, w, -0.0076224613f);
    p = __builtin_fmaf(p, w, 0.00943887047f);
    p = __builtin_fmaf(p, w, 1.00167406f);
    p = __builtin_fmaf(p, w, 2.83297682f);
  }
  return p * x;
}

__device__ __forceinline__ float bits_to_normal(uint32_t bits) {
  const float MINVAL = -0.999999940395355224609375f;
  uint32_t fb = (bits >> 9) | 0x3F800000u;
  float f01 = __uint_as_float(fb) - 1.0f;
  float u = f01 * 2.0f + MINVAL;
  u = fmaxf(u, MINVAL);
  return 1.41421356237309515f * erfinv_xla(u);
}

#define DTF  0.00396825396825396826f
#define SQDT 0.06299407883487120442f
#define TSTEP (1.0f / 2519.0f)

// ---------------- Phase 1: mean_dW[b][s] — fully parallel ----------------
// One wave per (b,s): 64 lanes x 4 normals, butterfly-reduce, lane0 writes.
__global__ __launch_bounds__(256)
void vasicek_phase1_meandw(float* __restrict__ ws) {
  const int tid = threadIdx.x;
  const int lane = tid & 63;
  const int wv = tid >> 6;
  const int wid = blockIdx.x * 4 + wv;          // 0 .. 64*2520-1
  const int b = wid / NSTEPS;
  const int s = wid - b * NSTEPS;

  uint32_t kA, kB;
  tf2x32(0u, 1u, 0u, (uint32_t)s, kA, kB);      // split(key(1))[s]

  float sum = 0.f;
#pragma unroll
  for (int i = 0; i < 4; ++i) {
    uint32_t cnt = (uint32_t)(b * NQ + lane + i * 64);
    uint32_t q0, q1;
    tf2x32(kA, kB, 0u, cnt, q0, q1);
    float dw = bits_to_normal(q0 ^ q1) * SQDT;
    sum += dw;
  }
  sum += __shfl_xor(sum, 32, 64); sum += __shfl_xor(sum, 16, 64);
  sum += __shfl_xor(sum, 8, 64);  sum += __shfl_xor(sum, 4, 64);
  sum += __shfl_xor(sum, 2, 64);  sum += __shfl_xor(sum, 1, 64);
  if (lane == 0) ws[b * NSTEPS + s] = sum * (1.0f / 256.0f);
}

// ---------------- Phase 2: scalar mean recursion, 64 blocks x 512 ----------
// thread t: mlp = t>>8 (0=mu,1=si); idx = t&255; j = idx&127; half = idx>>7.
// Each thread holds 64 W2 values (rows half*64..+63 of column j) in 4 f16v.
__global__
__attribute__((amdgpu_flat_work_group_size(512, 512)))
__attribute__((amdgpu_waves_per_eu(2, 2)))
void vasicek_phase2_scan(
    const float* __restrict__ X, const float* __restrict__ r_ult,
    const float* __restrict__ mats,
    const float* __restrict__ Wp, const float* __restrict__ bp,
    const float* __restrict__ ln_g, const float* __restrict__ ln_b,
    const float* __restrict__ muW1, const float* __restrict__ mub1,
    const float* __restrict__ muW2, const float* __restrict__ mub2,
    const float* __restrict__ muW3, const float* __restrict__ mub3,
    const float* __restrict__ siW1, const float* __restrict__ sib1,
    const float* __restrict__ siW2, const float* __restrict__ sib2,
    const float* __restrict__ siW3, const float* __restrict__ sib3,
    const float* __restrict__ ws, float* __restrict__ out) {
  const int b = blockIdx.x;
  const int t = threadIdx.x;
  const int lane = t & 63;
  const int wvv = t >> 6;

  __shared__ float part[256];
  __shared__ float mbuf[64];
  __shared__ float ctx_lds[192];
  __shared__ __align__(16) float h1_lds[256];
  __shared__ float p2[512];
  __shared__ float msum[4];
  __shared__ float meanw[NSTEPS];

  // stage mean_dW for this batch into LDS
  for (int i = t; i < NSTEPS; i += 512) meanw[i] = ws[b * NSTEPS + i];

  // ---- context aggregator (threads 0..255, i.e. waves 0-3) ----
  float h[64];
  if (t < 256) {
    float x0 = X[(b * NT + t) * 2 + 0];
    float x1 = X[(b * NT + t) * 2 + 1];
    float s = 0.f;
#pragma unroll
    for (int c = 0; c < 64; ++c) {
      float pre = __builtin_fmaf(x1, Wp[64 + c], x0 * Wp[c]) + bp[c];
      h[c] = eigen_tanh(pre);
      s += h[c];
    }
    float m = s * 0.015625f;
    float vs = 0.f;
#pragma unroll
    for (int c = 0; c < 64; ++c) { float d = h[c] - m; vs = __builtin_fmaf(d, d, vs); }
    float den = sqrtf(vs * 0.015625f + 1e-5f);
#pragma unroll
    for (int c = 0; c < 64; ++c)
      h[c] = ((h[c] - m) / den) * ln_g[c] + ln_b[c];
#pragma unroll
    for (int c = 0; c < 64; ++c) {
      float v = h[c];
      v += __shfl_xor(v, 32, 64); v += __shfl_xor(v, 16, 64);
      v += __shfl_xor(v, 8, 64);  v += __shfl_xor(v, 4, 64);
      v += __shfl_xor(v, 2, 64);  v += __shfl_xor(v, 1, 64);
      if (lane == 0) part[wvv * 64 + c] = v;
    }
  }
  __syncthreads();
  if (t < 64) {
    float m = ((part[t] + part[64 + t]) + (part[128 + t] + part[192 + t])) * (1.0f / 256.0f);
    mbuf[t] = m;
    ctx_lds[t] = m;
  }
  __syncthreads();
  if (t < 256) {
#pragma unroll
    for (int c = 0; c < 64; ++c) {
      float d = h[c] - mbuf[c];
      float v = d * d;
      v += __shfl_xor(v, 32, 64); v += __shfl_xor(v, 16, 64);
      v += __shfl_xor(v, 8, 64);  v += __shfl_xor(v, 4, 64);
      v += __shfl_xor(v, 2, 64);  v += __shfl_xor(v, 1, 64);
      if (lane == 0) part[wvv * 64 + c] = v;
    }
    if (t == 255) {
#pragma unroll
      for (int c = 0; c < 64; ++c) ctx_lds[128 + c] = h[c];
    }
  }
  __syncthreads();
  if (t < 64) {
    float vs = (part[t] + part[64 + t]) + (part[128 + t] + part[192 + t]);
    ctx_lds[64 + t] = sqrtf(vs / 255.0f);
  }
  __syncthreads();

  // ---- per-thread constants ----
  const int mlp = t >> 8;          // 0 = mu, 1 = si
  const int idx = t & 255;
  const int j = idx & 127;
  const int half = idx >> 7;       // wave-uniform
  const float* W1 = mlp == 0 ? muW1 : siW1;
  const float* W2 = mlp == 0 ? muW2 : siW2;
  float c1 = (mlp == 0 ? mub1 : sib1)[j];
  for (int c = 0; c < 192; ++c)
    c1 = __builtin_fmaf(ctx_lds[c], W1[(2 + c) * 128 + j], c1);
  const float w10 = W1[j];
  const float w11 = W1[128 + j];
  const float b2s = (mlp == 0 ? mub2 : sib2)[j];
  const float w3s = (mlp == 0 ? muW3 : siW3)[j];
  const float b3mu = mub3[0];
  const float b3si = sib3[0];

  // W2 half-column: rows half*64 .. half*64+63 of column j (64 floats)
  f16v w2a, w2b, w2c, w2d;
#pragma unroll
  for (int k = 0; k < 16; ++k) w2a[k] = W2[(half * 64 +  0 + k) * 128 + j];
#pragma unroll
  for (int k = 0; k < 16; ++k) w2b[k] = W2[(half * 64 + 16 + k) * 128 + j];
#pragma unroll
  for (int k = 0; k < 16; ++k) w2c[k] = W2[(half * 64 + 32 + k) * 128 + j];
#pragma unroll
  for (int k = 0; k < 16; ++k) w2d[k] = W2[(half * 64 + 48 + k) * 128 + j];

  float r_mean = r_ult[b];
  float area = 0.f;

#pragma unroll 1
  for (int s = 0; s < NSTEPS; ++s) {
    const float tval = TSTEP * (float)s;
    if (idx < 128) {  // owner threads compute h1 for (mlp, j)
      float pre = __builtin_fmaf(tval, w11, __builtin_fmaf(r_mean, w10, c1));
      h1_lds[mlp * 128 + idx] = gelu_exact(pre);
    }
    __syncthreads();  // barrier A

    // half-dot: 64 MACs against broadcast h1
    const float* hb = h1_lds + mlp * 128 + half * 64;
    float a0 = 0.f, a1 = 0.f, a2 = 0.f, a3 = 0.f;
#define HSEG(V, OFF) { \
    f4v h4; \
    h4 = *(const f4v*)(hb + (OFF) + 0); \
    a0 = __builtin_fmaf(h4[0], V[0],  a0); \
    a1 = __builtin_fmaf(h4[1], V[1],  a1); \
    a2 = __builtin_fmaf(h4[2], V[2],  a2); \
    a3 = __builtin_fmaf(h4[3], V[3],  a3); \
    h4 = *(const f4v*)(hb + (OFF) + 4); \
    a0 = __builtin_fmaf(h4[0], V[4],  a0); \
    a1 = __builtin_fmaf(h4[1], V[5],  a1); \
    a2 = __builtin_fmaf(h4[2], V[6],  a2); \
    a3 = __builtin_fmaf(h4[3], V[7],  a3); \
    h4 = *(const f4v*)(hb + (OFF) + 8); \
    a0 = __builtin_fmaf(h4[0], V[8],  a0); \
    a1 = __builtin_fmaf(h4[1], V[9],  a1); \
    a2 = __builtin_fmaf(h4[2], V[10], a2); \
    a3 = __builtin_fmaf(h4[3], V[11], a3); \
    h4 = *(const f4v*)(hb + (OFF) + 12); \
    a0 = __builtin_fmaf(h4[0], V[12], a0); \
    a1 = __builtin_fmaf(h4[1], V[13], a1); \
    a2 = __builtin_fmaf(h4[2], V[14], a2); \
    a3 = __builtin_fmaf(h4[3], V[15], a3); \
    }
    HSEG(w2a, 0) HSEG(w2b, 16) HSEG(w2c, 32) HSEG(w2d, 48)
#undef HSEG
    p2[t] = (a0 + a1) + (a2 + a3);
    __syncthreads();  // barrier B

    if (idx < 128) {
      float h2 = (p2[t] + p2[t + 128]) + b2s;
      float p = gelu_exact(h2) * w3s;
      p += __shfl_xor(p, 32, 64); p += __shfl_xor(p, 16, 64);
      p += __shfl_xor(p, 8, 64);  p += __shfl_xor(p, 4, 64);
      p += __shfl_xor(p, 2, 64);  p += __shfl_xor(p, 1, 64);
      if (lane == 0) msum[(wvv & 1) + ((wvv >> 2) << 1)] = p;
    }
    __syncthreads();  // barrier C

    const float mu = (msum[0] + msum[1]) + b3mu;
    const float si = softplus_jax((msum[2] + msum[3]) + b3si) + 1e-5f;
    r_mean = __fadd_rn(__fadd_rn(r_mean, __fmul_rn(mu, DTF)),
                       __fmul_rn(si, meanw[s]));
    area = __fadd_rn(area, __fmul_rn(r_mean, DTF));
  }

  if (t < NMAT) {
    float mx = mats[0];
#pragma unroll
    for (int i = 1; i < NMAT; ++i) mx = fmaxf(mx, mats[i]);
    const float m = mats[t];
    const float frac = m / (mx + 1e-12f);
    out[b * NMAT + t] = (area * frac) / (m + 1e-12f);
  }
}

extern "C" void kernel_launch(void* const* d_in, const int* in_sizes, int n_in,
                              void* d_out, int out_size, void* d_ws, size_t ws_size,
                              hipStream_t stream) {
  (void)in_sizes; (void)n_in; (void)ws_size; (void)out_size;
  const float* X      = (const float*)d_in[0];
  const float* r_ult  = (const float*)d_in[1];
  const float* mats   = (const float*)d_in[2];
  const float* Wp     = (const float*)d_in[3];
  const float* bp     = (const float*)d_in[4];
  const float* ln_g   = (const float*)d_in[5];
  const float* ln_b   = (const float*)d_in[6];
  const float* muW1   = (const float*)d_in[7];
  const float* mub1   = (const float*)d_in[8];
  const float* muW2   = (const float*)d_in[9];
  const float* mub2   = (const float*)d_in[10];
  const float* muW3   = (const float*)d_in[11];
  const float* mub3   = (const float*)d_in[12];
  const float* siW1   = (const float*)d_in[13];
  const float* sib1   = (const float*)d_in[14];
  const float* siW2   = (const float*)d_in[15];
  const float* sib2   = (const float*)d_in[16];
  const float* siW3   = (const float*)d_in[17];
  const float* sib3   = (const float*)d_in[18];
  float* ws = (float*)d_ws;   // needs 64*2520*4 = 645,120 bytes

  hipLaunchKernelGGL(vasicek_phase1_meandw,
                     dim3(NB * NSTEPS / 4), dim3(256), 0, stream, ws);
  hipLaunchKernelGGL(vasicek_phase2_scan,
                     dim3(NB), dim3(512), 0, stream,
                     X, r_ult, mats, Wp, bp, ln_g, ln_b,
                     muW1, mub1, muW2, mub2, muW3, mub3,
                     siW1, sib1, siW2, sib2, siW3, sib3,
                     ws, (float*)d_out);
}